// Round 6
// baseline (11.247 us; speedup 1.0000x reference)
//
#include <hip/hip_runtime.h>
#include <hip/hip_bf16.h>

#define BB 8
#define TT 2048
#define FF 64
#define LL 48
#define TB 64            // tokens per block
#define RE (TB + LL)     // extended He rows: t0-48 .. t0+63 (= 112)
#define NW 8
#define NT (NW * 64)

typedef __attribute__((ext_vector_type(8))) short bf16x8;   // MFMA A/B frag (8 bf16)
typedef __attribute__((ext_vector_type(4))) float f32x4;    // MFMA C/D frag

// LDS layout (bytes). Tiles: row stride = 8 chunks * 16B, XOR-swizzle chunk ^= (row&7).
#define HE_HI 0          // He_ext hi [112][64] bf16 (A-op Q/S; strided B-op ctx)
#define HE_LO 14336      // He_ext lo
#define QQ_HI 28672      // Q hi [64][64] bf16 (B-op S: rows=tok, k=g)
#define QQ_LO 36864      // Q lo
#define WT_HI 45056      // W^T hi [64 n][64 g] bf16 (B-op Q: rows=n, k=g)  [live phases 1-2]
#define WT_LO 53248      // W^T lo                                          [live phases 1-2]
#define PT    45056      // P^T banded [64 tok][8ch] bf16 (A-op ctx)        [live phases 3-4, aliases WT]
#define SMEM_BYTES 61440

__device__ __forceinline__ unsigned short f2b(float x) {    // fp32 -> bf16 RNE (HW cvt)
    return __builtin_bit_cast(unsigned short, __float2bfloat16(x));
}
__device__ __forceinline__ float b2f(unsigned short h) {
    return __bfloat162float(__builtin_bit_cast(__hip_bfloat16, h));
}

__global__ __launch_bounds__(NT, 2)
void ContextBlock_kernel(const float* __restrict__ he,
                         const float* __restrict__ Wm,
                         const float* __restrict__ bias,
                         float* __restrict__ out)
{
    __shared__ __align__(16) unsigned char smem[SMEM_BYTES];

    const int tid  = threadIdx.x;
    const int wave = tid >> 6;
    const int lane = tid & 63;
    const int bb   = blockIdx.y;
    const int t0   = blockIdx.x * TB;

    const float* heb = he + (size_t)bb * TT * FF;

    // ---- phase 1: stage He_ext hi/lo (swizzled) + W^T hi/lo ----
    const float4* he4 = (const float4*)heb;
    for (int e = tid; e < RE * 16; e += NT) {               // 112 rows x 16 float4-chunks
        int r = e >> 4, c4 = e & 15;
        int g = t0 - LL + r; g = g < 0 ? 0 : g;             // clamp = reference's clip(rel,0,..)
        float4 v = he4[g * 16 + c4];
        unsigned short h0 = f2b(v.x), h1 = f2b(v.y), h2 = f2b(v.z), h3 = f2b(v.w);
        unsigned short l0 = f2b(v.x - b2f(h0)), l1 = f2b(v.y - b2f(h1));
        unsigned short l2 = f2b(v.z - b2f(h2)), l3 = f2b(v.w - b2f(h3));
        unsigned long long pkh = (unsigned long long)h0 | ((unsigned long long)h1 << 16)
                               | ((unsigned long long)h2 << 32) | ((unsigned long long)h3 << 48);
        unsigned long long pkl = (unsigned long long)l0 | ((unsigned long long)l1 << 16)
                               | ((unsigned long long)l2 << 32) | ((unsigned long long)l3 << 48);
        int off = r * 128 + ((((c4 >> 1) ^ (r & 7)) << 4)) + ((c4 & 1) << 3);
        *(unsigned long long*)(smem + HE_HI + off) = pkh;
        *(unsigned long long*)(smem + HE_LO + off) = pkl;
    }
    const float4* w4 = (const float4*)Wm;
    for (int e = tid; e < 1024; e += NT) {                  // W[g][n]: 1024 float4 (4 consecutive n)
        int g = e >> 4, n0 = (e & 15) * 4;
        float4 v = w4[e];
        float vv[4] = {v.x, v.y, v.z, v.w};
        #pragma unroll
        for (int j = 0; j < 4; ++j) {
            int n = n0 + j;
            unsigned short hi = f2b(vv[j]);
            unsigned short lo = f2b(vv[j] - b2f(hi));
            int off = n * 128 + ((((g >> 3) ^ (n & 7)) << 4)) + ((g & 7) << 1);
            *(unsigned short*)(smem + WT_HI + off) = hi;
            *(unsigned short*)(smem + WT_LO + off) = lo;
        }
    }
    __syncthreads();

    const int l15 = lane & 15;
    const int lhi = lane >> 4;

    // ---- phase 2: Q = He*W + b (split-bf16; W^T from LDS) -> Q hi/lo ----
    #pragma unroll
    for (int s = 0; s < 2; ++s) {
        int q = wave * 2 + s;
        int mt = q >> 2, nt = q & 3;
        f32x4 acc = (f32x4){0.f, 0.f, 0.f, 0.f};
        int arow = LL + mt * 16 + l15;                      // He row of token
        int colg = nt * 16 + l15;                           // output col n
        #pragma unroll
        for (int kf = 0; kf < 2; ++kf) {
            int chunk = 4 * kf + lhi;
            int offA = arow * 128 + ((chunk ^ (arow & 7)) << 4);
            int offB = colg * 128 + ((chunk ^ (colg & 7)) << 4);
            bf16x8 ah = *(const bf16x8*)(smem + HE_HI + offA);
            bf16x8 al = *(const bf16x8*)(smem + HE_LO + offA);
            bf16x8 bh = *(const bf16x8*)(smem + WT_HI + offB);
            bf16x8 bl = *(const bf16x8*)(smem + WT_LO + offB);
            acc = __builtin_amdgcn_mfma_f32_16x16x32_bf16(ah, bh, acc, 0, 0, 0);
            acc = __builtin_amdgcn_mfma_f32_16x16x32_bf16(ah, bl, acc, 0, 0, 0);
            acc = __builtin_amdgcn_mfma_f32_16x16x32_bf16(al, bh, acc, 0, 0, 0);
        }
        float bv = bias[colg];
        #pragma unroll
        for (int i = 0; i < 4; ++i) {                       // C: row=tok=(lane>>4)*4+i, col=n
            int tok = mt * 16 + lhi * 4 + i;
            float qv = acc[i] + bv;
            unsigned short hi = f2b(qv);
            unsigned short lo = f2b(qv - b2f(hi));
            int off = tok * 128 + ((((colg >> 3) ^ (tok & 7)) << 4)) + ((colg & 7) << 1);
            *(unsigned short*)(smem + QQ_HI + off) = hi;
            *(unsigned short*)(smem + QQ_LO + off) = lo;
        }
    }
    __syncthreads();

    // ---- phase 3: waves 0-3: full-band scores + in-wave softmax -> banded P^T ----
    if (wave < 4) {
        const int ct   = wave;                              // col-tile (16 tokens)
        const int tokc = ct * 16 + l15;                     // this lane's token column
        float sc[4][4];                                     // [u rowtile][i]
        float m = -1e30f;
        #pragma unroll
        for (int u = 0; u < 4; ++u) {
            int arow = (ct + u) * 16 + l15;                 // r_ext row of A
            f32x4 acc = (f32x4){0.f, 0.f, 0.f, 0.f};
            #pragma unroll
            for (int kf = 0; kf < 2; ++kf) {
                int chunk = 4 * kf + lhi;
                int offA = arow * 128 + ((chunk ^ (arow & 7)) << 4);
                int offB = tokc * 128 + ((chunk ^ (tokc & 7)) << 4);
                bf16x8 ah = *(const bf16x8*)(smem + HE_HI + offA);
                bf16x8 al = *(const bf16x8*)(smem + HE_LO + offA);
                bf16x8 bh = *(const bf16x8*)(smem + QQ_HI + offB);
                bf16x8 bl = *(const bf16x8*)(smem + QQ_LO + offB);
                acc = __builtin_amdgcn_mfma_f32_16x16x32_bf16(ah, bh, acc, 0, 0, 0);
                acc = __builtin_amdgcn_mfma_f32_16x16x32_bf16(ah, bl, acc, 0, 0, 0);
                acc = __builtin_amdgcn_mfma_f32_16x16x32_bf16(al, bh, acc, 0, 0, 0);
            }
            #pragma unroll
            for (int i = 0; i < 4; ++i) {
                int r_ext = (ct + u) * 16 + lhi * 4 + i;
                int l = r_ext - tokc;
                bool valid = (t0 == 0 && tokc == 0) ? (r_ext == LL - 1)
                                                    : (l >= 0 && l < LL && (t0 + r_ext) >= LL);
                float sv = valid ? acc[i] : -1e30f;
                sc[u][i] = sv;
                m = fmaxf(m, sv);
            }
        }
        m = fmaxf(m, __shfl_xor(m, 16));
        m = fmaxf(m, __shfl_xor(m, 32));                    // full column max (64 rows)
        float sum = 0.f;
        #pragma unroll
        for (int u = 0; u < 4; ++u)
            #pragma unroll
            for (int i = 0; i < 4; ++i) {
                float p = __expf(sc[u][i] - m);
                sc[u][i] = p;
                sum += p;
            }
        sum += __shfl_xor(sum, 16);
        sum += __shfl_xor(sum, 32);
        float invT = 1.0f / sum;
        #pragma unroll
        for (int u = 0; u < 4; ++u) {
            // local k = 16u + 4*lhi + i -> chunk c = 2u + (lhi>>1), byte (lhi&1)*8 + i*2
            unsigned short w0 = f2b(sc[u][0] * invT);
            unsigned short w1 = f2b(sc[u][1] * invT);
            unsigned short w2 = f2b(sc[u][2] * invT);
            unsigned short w3 = f2b(sc[u][3] * invT);
            unsigned long long pk = (unsigned long long)w0 | ((unsigned long long)w1 << 16)
                                  | ((unsigned long long)w2 << 32) | ((unsigned long long)w3 << 48);
            int c = 2 * u + (lhi >> 1);
            *(unsigned long long*)(smem + PT + tokc * 128
                + ((c ^ (tokc & 7)) << 4) + ((lhi & 1) << 3)) = pk;
        }
    }
    __syncthreads();

    // ---- phase 4: ctx = P^T * He (banded K; B read strided from HE_HI) -> global ----
    #pragma unroll
    for (int s2 = 0; s2 < 2; ++s2) {
        int q = wave * 2 + s2;
        int mt = q >> 2, nt = q & 3;
        int tokrow = mt * 16 + l15;                         // A row = token
        int fcol   = nt * 16 + l15;                         // B col = f
        f32x4 acc = (f32x4){0.f, 0.f, 0.f, 0.f};
        #pragma unroll
        for (int kk = 0; kk < 2; ++kk) {
            int cA = kk * 4 + lhi;                          // local k chunk
            bf16x8 a = *(const bf16x8*)(smem + PT + tokrow * 128
                + ((cA ^ (tokrow & 7)) << 4));
            bf16x8 b;
            #pragma unroll
            for (int j = 0; j < 8; ++j) {                   // B[k][n] = He[r][f], r strided
                int r = mt * 16 + kk * 32 + lhi * 8 + j;
                b[j] = *(const short*)(smem + HE_HI + r * 128
                    + ((((fcol >> 3) ^ (r & 7)) << 4)) + ((fcol & 7) << 1));
            }
            acc = __builtin_amdgcn_mfma_f32_16x16x32_bf16(a, b, acc, 0, 0, 0);
        }
        #pragma unroll
        for (int i = 0; i < 4; ++i) {
            int tk = mt * 16 + lhi * 4 + i;
            out[((size_t)bb * TT + t0 + tk) * FF + fcol] = acc[i];
        }
    }
}

extern "C" void kernel_launch(void* const* d_in, const int* in_sizes, int n_in,
                              void* d_out, int out_size, void* d_ws, size_t ws_size,
                              hipStream_t stream) {
    const float* he   = (const float*)d_in[0];
    const float* Wm   = (const float*)d_in[1];
    const float* bias = (const float*)d_in[2];
    float* out        = (float*)d_out;

    dim3 grid(TT / TB, BB);   // 32 x 8 = 256 blocks
    ContextBlock_kernel<<<grid, NT, 0, stream>>>(he, Wm, bias, out);
}